// Round 1
// baseline (763.822 us; speedup 1.0000x reference)
//
#include <hip/hip_runtime.h>
#include <hip/hip_bf16.h>
#include <cstdint>
#include <cstddef>

#define D 128
#define SBLK 512

typedef __attribute__((ext_vector_type(8))) short short8;
typedef __attribute__((ext_vector_type(4))) float f32x4;

__device__ __forceinline__ unsigned short f2bf(float f) {
    union { float f; unsigned u; } v; v.f = f;
    unsigned r = v.u + 0x7FFF + ((v.u >> 16) & 1);   // RNE
    return (unsigned short)(r >> 16);
}
__device__ __forceinline__ float bflo(unsigned p) {
    union { unsigned u; float f; } v; v.u = p << 16; return v.f;
}
__device__ __forceinline__ float bfhi(unsigned p) {
    union { unsigned u; float f; } v; v.u = p & 0xFFFF0000u; return v.f;
}

// ---- detect whether edge_index arrived as int64 (all hi-dwords zero) ----
__global__ void k_detect(const unsigned* __restrict__ ei, int E, int* flag) {
    if (threadIdx.x == 0 && blockIdx.x == 0) {
        int n = E < 256 ? E : 256;
        int allz = 1;
        for (int k = 0; k < n; ++k) {
            if (ei[2 * k + 1] != 0u) { allz = 0; break; }
        }
        *flag = allz;
    }
}

// ---- W (f32 [D][D]) -> bf16, same layout ----
__global__ void k_wcvt(const float* __restrict__ W, unsigned short* __restrict__ Wbf) {
    int i = blockIdx.x * 256 + threadIdx.x;
    if (i < D * D) Wbf[i] = f2bf(W[i]);
}

// ---- GEMM: h[M][128] = x[M][128] @ W^T, bf16 MFMA, h stored bf16 ----
__global__ __launch_bounds__(256) void k_gemm(const float* __restrict__ x,
                                              const unsigned short* __restrict__ Wbf,
                                              unsigned short* __restrict__ h, int M) {
    int wave = threadIdx.x >> 6, lane = threadIdx.x & 63;
    int m0 = blockIdx.x * 64 + wave * 16;
    int lr = lane & 15;       // row-in-tile (A), col-in-tile (B/D)
    int lg = lane >> 4;       // k-group
    f32x4 acc[8];
#pragma unroll
    for (int i = 0; i < 8; ++i) acc[i] = (f32x4){0.f, 0.f, 0.f, 0.f};

    int row = m0 + lr;
    int rowc = row < M ? row : M - 1;
    const float* xr = x + (size_t)rowc * D;

#pragma unroll
    for (int ks = 0; ks < 4; ++ks) {
        int k0 = ks * 32 + lg * 8;
        float4 a0 = *(const float4*)(xr + k0);
        float4 a1 = *(const float4*)(xr + k0 + 4);
        short8 af;
        af[0] = (short)f2bf(a0.x); af[1] = (short)f2bf(a0.y);
        af[2] = (short)f2bf(a0.z); af[3] = (short)f2bf(a0.w);
        af[4] = (short)f2bf(a1.x); af[5] = (short)f2bf(a1.y);
        af[6] = (short)f2bf(a1.z); af[7] = (short)f2bf(a1.w);
#pragma unroll
        for (int nt = 0; nt < 8; ++nt) {
            // B[k][n] = W[n][k]; lane needs 8 consecutive k at row (nt*16+lr): contiguous in W
            short8 bf = *(const short8*)(Wbf + (size_t)(nt * 16 + lr) * D + k0);
            acc[nt] = __builtin_amdgcn_mfma_f32_16x16x32_bf16(af, bf, acc[nt], 0, 0, 0);
        }
    }
#pragma unroll
    for (int nt = 0; nt < 8; ++nt) {
#pragma unroll
        for (int r = 0; r < 4; ++r) {
            int rr = m0 + lg * 4 + r;
            if (rr < M) h[(size_t)rr * D + nt * 16 + lr] = f2bf(acc[nt][r]);
        }
    }
}

// ---- degree count over dst ----
__global__ void k_deg(const int* __restrict__ ei, int E, const int* __restrict__ flagp,
                      int* __restrict__ deg) {
    int f64 = *flagp;
    for (int e = blockIdx.x * blockDim.x + threadIdx.x; e < E; e += gridDim.x * blockDim.x) {
        int d = f64 ? ei[2 * (E + e)] : ei[E + e];
        atomicAdd(&deg[d], 1);
    }
}

// ---- hierarchical exclusive scan: per-chunk (1024) local scan ----
__global__ void k_scan1(const int* __restrict__ deg, int* __restrict__ rowoff,
                        int* __restrict__ ctot, int N) {
    __shared__ int sh[1024];
    int t = threadIdx.x;
    int i = blockIdx.x * 1024 + t;
    int v = (i < N) ? deg[i] : 0;
    sh[t] = v;
    __syncthreads();
    for (int off = 1; off < 1024; off <<= 1) {
        int a = (t >= off) ? sh[t - off] : 0;
        __syncthreads();
        sh[t] += a;
        __syncthreads();
    }
    if (i < N) rowoff[i] = sh[t] - v;           // exclusive within chunk
    if (t == 1023) ctot[blockIdx.x] = sh[1023];
}

__global__ void k_scan2(const int* __restrict__ ctot, int* __restrict__ cbase, int nchunks) {
    if (threadIdx.x == 0 && blockIdx.x == 0) {
        int run = 0;
        for (int c = 0; c < nchunks; ++c) { cbase[c] = run; run += ctot[c]; }
    }
}

__global__ void k_finoff(int* __restrict__ rowoff, int* __restrict__ cursor,
                         const int* __restrict__ cbase, const int* __restrict__ deg,
                         float* __restrict__ dinv, int N, int E) {
    int i = blockIdx.x * 256 + threadIdx.x;
    if (i < N) {
        int ro = rowoff[i] + cbase[i >> 10];
        rowoff[i] = ro;
        cursor[i] = ro;
        int d = deg[i];
        dinv[i] = d > 0 ? rsqrtf((float)d) : 0.0f;
    }
    if (i == 0) rowoff[N] = E;
}

// ---- CSR fill: sorted-by-dst src list ----
__global__ void k_fill(const int* __restrict__ ei, int E, const int* __restrict__ flagp,
                       int* __restrict__ cursor, int* __restrict__ csrc) {
    int f64 = *flagp;
    for (int e = blockIdx.x * blockDim.x + threadIdx.x; e < E; e += gridDim.x * blockDim.x) {
        int s = f64 ? ei[2 * e] : ei[e];
        int d = f64 ? ei[2 * (E + e)] : ei[E + e];
        int pos = atomicAdd(&cursor[d], 1);
        csrc[pos] = s;
    }
}

// ---- aggregation: 1 wave per node; lane owns 2 cols (bf16x2 dword) ----
__global__ __launch_bounds__(256) void k_agg(const unsigned* __restrict__ h,
                                             const int* __restrict__ csrc,
                                             const int* __restrict__ rowoff,
                                             const float* __restrict__ dinv,
                                             float2* __restrict__ out, int N) {
    int wave = threadIdx.x >> 6, lane = threadIdx.x & 63;
    int node = blockIdx.x * 4 + wave;
    if (node >= N) return;
    int beg = rowoff[node], end = rowoff[node + 1];
    float ax = 0.f, ay = 0.f;
    int i = beg;
    for (; i + 4 <= end; i += 4) {
        int s0 = csrc[i], s1 = csrc[i + 1], s2 = csrc[i + 2], s3 = csrc[i + 3];
        float w0 = dinv[s0], w1 = dinv[s1], w2 = dinv[s2], w3 = dinv[s3];
        unsigned p0 = h[(size_t)s0 * 64 + lane];
        unsigned p1 = h[(size_t)s1 * 64 + lane];
        unsigned p2 = h[(size_t)s2 * 64 + lane];
        unsigned p3 = h[(size_t)s3 * 64 + lane];
        ax += w0 * bflo(p0); ay += w0 * bfhi(p0);
        ax += w1 * bflo(p1); ay += w1 * bfhi(p1);
        ax += w2 * bflo(p2); ay += w2 * bfhi(p2);
        ax += w3 * bflo(p3); ay += w3 * bfhi(p3);
    }
    for (; i < end; ++i) {
        int s = csrc[i];
        float w = dinv[s];
        unsigned p = h[(size_t)s * 64 + lane];
        ax += w * bflo(p); ay += w * bfhi(p);
    }
    float sd = dinv[node];
    out[(size_t)node * 64 + lane] = make_float2(ax * sd, ay * sd);
}

// ---- BN stats: block partials (sum, sumsq) per column ----
__global__ __launch_bounds__(256) void k_stats(const float* __restrict__ agg,
                                               float* __restrict__ part, int N) {
    int t = threadIdx.x;
    int c = t & 127, half = t >> 7;
    float s = 0.f, q = 0.f;
    for (int r = blockIdx.x * 2 + half; r < N; r += SBLK * 2) {
        float v = agg[(size_t)r * 128 + c];
        s += v; q += v * v;
    }
    __shared__ float sh[512];
    sh[t] = s; sh[256 + t] = q;
    __syncthreads();
    if (t < 128) {
        part[blockIdx.x * 256 + t]       = sh[t] + sh[t + 128];
        part[blockIdx.x * 256 + 128 + t] = sh[256 + t] + sh[256 + t + 128];
    }
}

__global__ void k_params(const float* __restrict__ part, const float* __restrict__ gamma,
                         const float* __restrict__ beta, float* __restrict__ params, int N) {
    int t = threadIdx.x;   // 256
    float a = 0.f;
    for (int b = 0; b < SBLK; ++b) a += part[b * 256 + t];
    __shared__ float sh[256];
    sh[t] = a;
    __syncthreads();
    if (t < 128) {
        float mean = sh[t] / (float)N;
        float var = sh[128 + t] / (float)N - mean * mean;
        var = var > 0.f ? var : 0.f;
        float sc = gamma[t] * rsqrtf(var + 1e-5f);
        params[t] = sc;
        params[128 + t] = beta[t] - mean * sc;
    }
}

// ---- finalize in-place: out = relu(agg*scale+shift) + x ----
__global__ __launch_bounds__(256) void k_final(float4* __restrict__ out,
                                               const float4* __restrict__ x,
                                               const float* __restrict__ params, int n4) {
    const float4* p4 = (const float4*)params;
    for (int i = blockIdx.x * 256 + threadIdx.x; i < n4; i += gridDim.x * 256) {
        int c = i & 31;
        float4 s = p4[c], b = p4[32 + c];
        float4 v = out[i], xv = x[i];
        float4 r;
        r.x = fmaxf(v.x * s.x + b.x, 0.f) + xv.x;
        r.y = fmaxf(v.y * s.y + b.y, 0.f) + xv.y;
        r.z = fmaxf(v.z * s.z + b.z, 0.f) + xv.z;
        r.w = fmaxf(v.w * s.w + b.w, 0.f) + xv.w;
        out[i] = r;
    }
}

extern "C" void kernel_launch(void* const* d_in, const int* in_sizes, int n_in,
                              void* d_out, int out_size, void* d_ws, size_t ws_size,
                              hipStream_t stream) {
    const float* x     = (const float*)d_in[0];
    const int*   ei    = (const int*)d_in[1];
    const float* W     = (const float*)d_in[2];
    const float* gamma = (const float*)d_in[3];
    const float* beta  = (const float*)d_in[4];

    int N = in_sizes[0] / D;
    int E = in_sizes[1] / 2;
    int nchunks = (N + 1023) / 1024;

    char* ws = (char*)d_ws;
    size_t off = 0;
    auto alloc = [&](size_t bytes) { size_t o = off; off = (off + bytes + 255) & ~(size_t)255; return o; };

    unsigned short* h    = (unsigned short*)(ws + alloc((size_t)N * D * 2));
    int*   csrc   = (int*)  (ws + alloc((size_t)E * 4));
    int*   deg    = (int*)  (ws + alloc((size_t)N * 4));
    float* dinv   = (float*)(ws + alloc((size_t)N * 4));
    int*   rowoff = (int*)  (ws + alloc((size_t)(N + 1) * 4));
    int*   cursor = (int*)  (ws + alloc((size_t)N * 4));
    int*   ctot   = (int*)  (ws + alloc((size_t)nchunks * 4));
    int*   cbase  = (int*)  (ws + alloc((size_t)nchunks * 4));
    float* part   = (float*)(ws + alloc((size_t)SBLK * 256 * 4));
    float* params = (float*)(ws + alloc(256 * 4));
    int*   flagp  = (int*)  (ws + alloc(4));
    unsigned short* Wbf = (unsigned short*)(ws + alloc((size_t)D * D * 2));

    float* outf = (float*)d_out;

    hipMemsetAsync(deg, 0, (size_t)N * 4, stream);
    k_detect<<<1, 64, 0, stream>>>((const unsigned*)ei, E, flagp);
    k_wcvt<<<(D * D + 255) / 256, 256, 0, stream>>>(W, Wbf);
    k_gemm<<<(N + 63) / 64, 256, 0, stream>>>(x, Wbf, h, N);
    k_deg<<<2048, 256, 0, stream>>>(ei, E, flagp, deg);
    k_scan1<<<nchunks, 1024, 0, stream>>>(deg, rowoff, ctot, N);
    k_scan2<<<1, 64, 0, stream>>>(ctot, cbase, nchunks);
    k_finoff<<<(N + 255) / 256, 256, 0, stream>>>(rowoff, cursor, cbase, deg, dinv, N, E);
    k_fill<<<2048, 256, 0, stream>>>(ei, E, flagp, cursor, csrc);
    k_agg<<<(N + 3) / 4, 256, 0, stream>>>((const unsigned*)h, csrc, rowoff, dinv,
                                           (float2*)d_out, N);
    k_stats<<<SBLK, 256, 0, stream>>>(outf, part, N);
    k_params<<<1, 256, 0, stream>>>(part, gamma, beta, params, N);
    k_final<<<2048, 256, 0, stream>>>((float4*)d_out, (const float4*)x, params,
                                      (N * D) / 4);
}